// Round 6
// baseline (97.600 us; speedup 1.0000x reference)
//
#include <hip/hip_runtime.h>
#include <float.h>

// NearestCluster: per-batch NN argmin.
// coords1 [L1=4096, N=8, C=3] f32 (refs), coords2 [L2=4096, N=8, C=3] f32 (queries)
// out int32: [L2*N] argmin idx over L1 per batch, then [L2*N] batch idx.
//
// Numerics (bit-exact numpy f32 chain, verified absmax=0 in R1/R2/R5):
//   qq = (q0*q0 + q1*q1) + q2*q2 ; rr likewise ; dot = ((q0r0)+(q1r1))+(q2r2)
//   d2 = (qq + rr) - 2*dot == fma(dot,-2,qq+rr)   (2*dot exact, single round)
// ties -> lowest index (strict <, ascending scan, lex merge).
//
// R2/R4/R5 post-mortem: time pinned ~45us across 2x arithmetic changes ->
// not arith-bound; op_sel asm forced operand movs; staging gather + barriers
// stalled. R6: 1 query/thread (components DUPLICATED in both v2f halves ->
// plain v_pk_* with no op_sel, no movs), 2 refs packed per op, Q=4 slots per
// thread. Refs in LDS SoA-pairs, half-wave broadcast reads (padded n-stride).
// Ref-split R=32 across blocks -> partials in d_ws -> tiny merge kernel.

typedef float v2f __attribute__((ext_vector_type(2)));

__device__ __forceinline__ v2f pk_mul(v2f a, v2f b) {
  v2f d; asm("v_pk_mul_f32 %0, %1, %2" : "=v"(d) : "v"(a), "v"(b)); return d;
}
__device__ __forceinline__ v2f pk_add(v2f a, v2f b) {
  v2f d; asm("v_pk_add_f32 %0, %1, %2" : "=v"(d) : "v"(a), "v"(b)); return d;
}
__device__ __forceinline__ v2f pk_fma(v2f a, v2f b, v2f c) {
  v2f d; asm("v_pk_fma_f32 %0, %1, %2, %3" : "=v"(d) : "v"(a), "v"(b), "v"(c)); return d;
}

constexpr int kL1 = 4096, kL2 = 4096, kN = 8;
constexpr int kNStrideV2 = 260;  // 64 pairs * 4 v2f + 4 pad -> n,n+1 on disjoint banks

// ---------------- main: per-(query, ref-split) partial argmin ----------------
__global__ __launch_bounds__(256, 4)
void nn_partial(const float* __restrict__ c1, const float* __restrict__ c2,
                uint2* __restrict__ part, int refsPerBlock) {
#pragma clang fp contract(off)
  __shared__ v2f lds[8 * kNStrideV2];  // 16.6 KB: [n][pair][x2,y2,z2,rr2]

  const int tid = threadIdx.x;
  const int bx = blockIdx.x;   // 0..31: qi-group of 128
  const int by = blockIdx.y;   // 0..R-1: ref split
  const int n = tid >> 5;      // 0..7 (32 consecutive lanes share n)
  const int qlane = tid & 31;

  // ---- 4 query slots per thread (same n, qi spaced by 32), np-rounded qq ----
  v2f qx[4], qy[4], qz[4], qq[4];
  int qi[4];
#pragma unroll
  for (int k = 0; k < 4; ++k) {
    qi[k] = bx * 128 + qlane + 32 * k;
    const float* p = c2 + (qi[k] * kN + n) * 3;
    const float a0 = p[0], a1 = p[1], a2 = p[2];
    const float s = __fadd_rn(
        __fadd_rn(__fmul_rn(a0, a0), __fmul_rn(a1, a1)), __fmul_rn(a2, a2));
    qx[k] = v2f{a0, a0}; qy[k] = v2f{a1, a1};
    qz[k] = v2f{a2, a2}; qq[k] = v2f{s, s};
  }
  const v2f cm2 = {-2.0f, -2.0f};

  float bd[4]; int bi[4];
#pragma unroll
  for (int k = 0; k < 4; ++k) { bd[k] = FLT_MAX; bi[k] = 0; }

  const int refBase = by * refsPerBlock;
  for (int c = 0; c < refsPerBlock; c += 128) {
    __syncthreads();
    // ---- stage 128 refs x 8 n as SoA pairs; 2 tasks/thread ----
#pragma unroll
    for (int tk = 0; tk < 2; ++tk) {
      const int id = tid + 256 * tk;   // 0..511
      const int pn = id & 7;           // task n
      const int pp = id >> 3;          // pair 0..63
      const int j0 = refBase + c + 2 * pp;
      const float* r0 = c1 + (j0 * kN + pn) * 3;
      const float* r1 = c1 + ((j0 + 1) * kN + pn) * 3;
      const float x0 = r0[0], y0 = r0[1], z0 = r0[2];
      const float x1 = r1[0], y1 = r1[1], z1 = r1[2];
      const float rr0 = __fadd_rn(
          __fadd_rn(__fmul_rn(x0, x0), __fmul_rn(y0, y0)), __fmul_rn(z0, z0));
      const float rr1 = __fadd_rn(
          __fadd_rn(__fmul_rn(x1, x1), __fmul_rn(y1, y1)), __fmul_rn(z1, z1));
      v2f* dst = lds + pn * kNStrideV2 + pp * 4;
      dst[0] = v2f{x0, x1}; dst[1] = v2f{y0, y1};
      dst[2] = v2f{z0, z1}; dst[3] = v2f{rr0, rr1};
    }
    __syncthreads();

    const int jb = refBase + c;
    const v2f* row = lds + n * kNStrideV2;
#pragma unroll 4
    for (int p = 0; p < 64; ++p) {
      const v2f x2 = row[p * 4 + 0];
      const v2f y2 = row[p * 4 + 1];
      const v2f z2 = row[p * 4 + 2];
      const v2f w2 = row[p * 4 + 3];
      const int j0 = jb + 2 * p;
#pragma unroll
      for (int k = 0; k < 4; ++k) {
        const v2f m0 = pk_mul(qx[k], x2);
        const v2f m1 = pk_mul(qy[k], y2);
        const v2f s01 = pk_add(m0, m1);
        const v2f m2 = pk_mul(qz[k], z2);
        const v2f dot = pk_add(s01, m2);
        const v2f A = pk_add(qq[k], w2);
        const v2f d2 = pk_fma(dot, cm2, A);  // round(A - 2*dot), bit-exact
        if (d2.x < bd[k]) { bd[k] = d2.x; bi[k] = j0; }
        if (d2.y < bd[k]) { bd[k] = d2.y; bi[k] = j0 + 1; }
      }
    }
  }

  // ---- partials: [by][n][qi], coalesced over qlane ----
#pragma unroll
  for (int k = 0; k < 4; ++k) {
    part[((by * 8 + n) * 4096) + qi[k]] =
        make_uint2(__float_as_uint(bd[k]), (unsigned)bi[k]);
  }
}

// ---------------- merge: lex-(d, idx) min over R partials ----------------
__global__ __launch_bounds__(256)
void nn_merge(const uint2* __restrict__ part, int* __restrict__ out, int R) {
  const int id = blockIdx.x * 256 + threadIdx.x;  // n*4096 + qi
  const int n = id >> 12;
  const int qi = id & 4095;
  float bd = FLT_MAX; int bi = 0;
  for (int r = 0; r < R; ++r) {
    const uint2 v = part[(r * 8 + n) * 4096 + qi];
    const float d = __uint_as_float(v.x);
    const int i = (int)v.y;
    if (d < bd || (d == bd && i < bi)) { bd = d; bi = i; }
  }
  out[qi * kN + n] = bi;
  out[kL2 * kN + qi * kN + n] = n;
}

extern "C" void kernel_launch(void* const* d_in, const int* in_sizes, int n_in,
                              void* d_out, int out_size, void* d_ws, size_t ws_size,
                              hipStream_t stream) {
  const float* c1 = (const float*)d_in[0];
  const float* c2 = (const float*)d_in[1];
  int* out = (int*)d_out;

  // Largest ref-split whose partial buffer fits the workspace (8 MB at R=32).
  int R = 32;
  while (R > 1 && (size_t)R * 8 * 4096 * sizeof(uint2) > ws_size) R >>= 1;
  const int refsPerBlock = kL1 / R;

  nn_partial<<<dim3(32, R), 256, 0, stream>>>(c1, c2, (uint2*)d_ws, refsPerBlock);
  nn_merge<<<dim3(32768 / 256), 256, 0, stream>>>((const uint2*)d_ws, out, R);
}

// Round 7
// 91.753 us; speedup vs baseline: 1.0637x; 1.0637x over previous
//
#include <hip/hip_runtime.h>
#include <float.h>

// NearestCluster: per-batch NN argmin.
// coords1 [L1=4096, N=8, C=3] f32 (refs), coords2 [L2=4096, N=8, C=3] f32 (queries)
// out int32: [L2*N] argmin idx over L1 per batch, then [L2*N] batch idx.
//
// Numerics (bit-exact numpy f32 chain, verified absmax=0 in R1/R2/R5/R6):
//   qq = (q0*q0 + q1*q1) + q2*q2 ; rr likewise ; dot = ((q0r0)+(q1r1))+(q2r2)
//   d2 = (qq + rr) - 2*dot == fma(dot,-2,qq+rr)   (2*dot exact, single round)
// ties -> lowest index (strict <, ascending scan, lex merges).
//
// R5 post-mortem: inline-asm v_pk_* cost MORE VALU issue than scalar (mov
// bloat from "=v" pair constraints) — 45us pinned. R6: d_ws poison fill
// (268MB, 41.5us) runs in the timed loop -> single kernel only.
// R7: native <2 x float> packed math, no asm. All operands are true v2f:
// refs pre-DUPLICATED in LDS ({x,x},{y,y},{z,z},{rr,rr}); 2 queries/v2f;
// fma via __builtin_elementwise_fma. 1024-ref chunks (32KB LDS), 1024 blocks.

typedef float v2f __attribute__((ext_vector_type(2)));

constexpr int kL1 = 4096, kL2 = 4096, kN = 8;
constexpr int kChunk = 1024;   // refs per LDS chunk: 2x16KB arrays = 32 KB

__global__ __launch_bounds__(256, 4)
void nearest_kernel(const float* __restrict__ c1, const float* __restrict__ c2,
                    int* __restrict__ out) {
#pragma clang fp contract(off)
  __shared__ float4 ldsA[kChunk];  // {x, x, y, y} per ref
  __shared__ float4 ldsB[kChunk];  // {z, z, rr, rr} per ref

  const int tid = threadIdx.x;
  const int n = blockIdx.y;
  const int wave = tid >> 6;    // 0..3
  const int lane = tid & 63;    // 0..63
  const int q0 = blockIdx.x * 32 + wave * 8;  // 8 queries per wave

  // ---- 4 slot-pairs of queries ({q_even, q_odd} per v2f), np-rounded qq ----
  v2f qx[4], qy[4], qz[4], qq[4];
#pragma unroll
  for (int i = 0; i < 4; ++i) {
    const float* p0 = c2 + ((q0 + 2 * i) * kN + n) * 3;
    const float* p1 = c2 + ((q0 + 2 * i + 1) * kN + n) * 3;
    const float a0 = p0[0], a1 = p0[1], a2 = p0[2];
    const float b0 = p1[0], b1 = p1[1], b2 = p1[2];
    qx[i] = v2f{a0, b0};
    qy[i] = v2f{a1, b1};
    qz[i] = v2f{a2, b2};
    qq[i] = v2f{
        __fadd_rn(__fadd_rn(__fmul_rn(a0, a0), __fmul_rn(a1, a1)),
                  __fmul_rn(a2, a2)),
        __fadd_rn(__fadd_rn(__fmul_rn(b0, b0), __fmul_rn(b1, b1)),
                  __fmul_rn(b2, b2))};
  }
  const v2f cm2 = {-2.0f, -2.0f};

  float bd[8];
  int bi[8];
#pragma unroll
  for (int i = 0; i < 8; ++i) { bd[i] = FLT_MAX; bi[i] = 0; }

  for (int c = 0; c < kL1 / kChunk; ++c) {
    __syncthreads();  // previous chunk's readers done before overwrite

    // ---- stage chunk: each thread preps 4 refs, duplicated-halves layout ----
#pragma unroll
    for (int k = 0; k < kChunk / 256; ++k) {
      const int ref = tid + 256 * k;
      const float* p = c1 + ((c * kChunk + ref) * kN + n) * 3;
      const float x = p[0], y = p[1], z = p[2];
      const float rr = __fadd_rn(
          __fadd_rn(__fmul_rn(x, x), __fmul_rn(y, y)), __fmul_rn(z, z));
      ldsA[ref] = make_float4(x, x, y, y);
      ldsB[ref] = make_float4(z, z, rr, rr);
    }
    __syncthreads();

    const int jb = c * kChunk + lane;
    // 16 steps: lane covers ref = lane + 64*s. Full unroll -> immediate LDS
    // offsets; 8 independent select chains hide ds_read latency.
#pragma unroll
    for (int s = 0; s < kChunk / 64; ++s) {
      const float4 a = ldsA[lane + 64 * s];   // {x,x,y,y}
      const float4 b = ldsB[lane + 64 * s];   // {z,z,rr,rr}
      const v2f rx = {a.x, a.y};
      const v2f ry = {a.z, a.w};
      const v2f rz = {b.x, b.y};
      const v2f rw = {b.z, b.w};
      const int j = jb + 64 * s;
#pragma unroll
      for (int i = 0; i < 4; ++i) {
        const v2f m0 = qx[i] * rx;
        const v2f m1 = qy[i] * ry;
        const v2f s01 = m0 + m1;
        const v2f m2 = qz[i] * rz;
        const v2f dot = s01 + m2;
        const v2f A = qq[i] + rw;
        const v2f d2 = __builtin_elementwise_fma(dot, cm2, A);  // A - 2*dot
        if (d2.x < bd[2 * i]) { bd[2 * i] = d2.x; bi[2 * i] = j; }
        if (d2.y < bd[2 * i + 1]) { bd[2 * i + 1] = d2.y; bi[2 * i + 1] = j; }
      }
    }
  }

  // ---- cross-lane merge (full wave butterfly), tie -> lower index ----
#pragma unroll
  for (int i = 0; i < 8; ++i) {
#pragma unroll
    for (int m = 1; m <= 32; m <<= 1) {
      const float od = __shfl_xor(bd[i], m);
      const int oi = __shfl_xor(bi[i], m);
      if (od < bd[i] || (od == bd[i] && oi < bi[i])) { bd[i] = od; bi[i] = oi; }
    }
  }

  if (lane == 0) {
#pragma unroll
    for (int i = 0; i < 8; ++i) {
      out[(q0 + i) * kN + n] = bi[i];
      out[kL2 * kN + (q0 + i) * kN + n] = n;
    }
  }
}

extern "C" void kernel_launch(void* const* d_in, const int* in_sizes, int n_in,
                              void* d_out, int out_size, void* d_ws, size_t ws_size,
                              hipStream_t stream) {
  const float* c1 = (const float*)d_in[0];
  const float* c2 = (const float*)d_in[1];
  int* out = (int*)d_out;
  dim3 grid(kL2 / 32, kN);  // 128 x 8 = 1024 blocks
  nearest_kernel<<<grid, dim3(256), 0, stream>>>(c1, c2, out);
}